// Round 7
// baseline (446.032 us; speedup 1.0000x reference)
//
#include <hip/hip_runtime.h>
#include <hip/hip_bf16.h>
#include <math.h>

#define B_   8
#define C_   32
#define H_   256
#define W_   256
#define NPIX (B_*C_*H_*W_)   // offset of logdet in d_out

// LDS tile: 2 staged rows x 20 px-slots x 32 ch bf16 (p = local px + 1;
// p=0 and p=17 are the halo columns, 18/19 pad). 2560 B total.
//   dword(r,p,g,d) = (r*20 + p)*16 + ((g ^ (p&3) ^ ((p>>2)&3)) << 2) + d
// where g = channel-octet (8 ch), d = dword within octet (2 ch each).
#define PW2   20
#define ROWB  (PW2*64)        // bytes per staged row

typedef __attribute__((ext_vector_type(8))) short short8;   // bf16x8 MFMA A/B frag
typedef __attribute__((ext_vector_type(4))) float f32x4;    // fp32x4 MFMA C/D frag

static __device__ __forceinline__ short f2bf(float f) {
    union { __hip_bfloat16 h; short s; } u; u.h = __float2bfloat16(f); return u.s;
}
static __device__ __forceinline__ int packbf(float a, float b) {
    return (int)(unsigned short)f2bf(a) | ((int)(unsigned short)f2bf(b) << 16);
}

// ---------------------------------------------------------------------------
// Prep: weight-norm -> bf16.
//   w1b[o*192 + tap*32 + c]                       (tap = kh*3+kw)
//   w2b[j*64 + slot]: hidden-dim permutation so conv2 B-frags are lane-local:
//     channel c (mt=c>>4, q=(c>>2)&3, reg=c&3) -> slot (mt>>1)*32+q*8+(mt&1)*4+reg
// ---------------------------------------------------------------------------
__global__ __launch_bounds__(64) void prep_kernel(
    const float* __restrict__ v1, const float* __restrict__ g1,
    const float* __restrict__ v2, const float* __restrict__ g2,
    short* __restrict__ w1b, short* __restrict__ w2b,
    float* __restrict__ logdet)
{
    const int t   = threadIdx.x;   // 0..63
    const int bid = blockIdx.x;    // 0..127
    if (bid < 64) {
        const int o = bid;
        float a0 = v1[o*192 + t];
        float a1 = v1[o*192 + t + 64];
        float a2 = v1[o*192 + t + 128];
        float s  = a0*a0 + a1*a1 + a2*a2;
        #pragma unroll
        for (int m = 32; m >= 1; m >>= 1) s += __shfl_xor(s, m, 64);
        const float inv = g1[o] / sqrtf(s);
        const int e0 = t, e1 = t + 64, e2 = t + 128;   // src idx = c*6 + tap
        w1b[o*192 + (e0%6)*32 + e0/6] = f2bf(a0*inv);
        w1b[o*192 + (e1%6)*32 + e1/6] = f2bf(a1*inv);
        w1b[o*192 + (e2%6)*32 + e2/6] = f2bf(a2*inv);
        if (bid == 0 && t < B_) logdet[t] = 0.f;       // zero logdet every launch
    } else {
        const int j = bid - 64;
        float a = v2[j*64 + t];
        float s = a*a;
        #pragma unroll
        for (int m = 32; m >= 1; m >>= 1) s += __shfl_xor(s, m, 64);
        const float inv = g2[j] / sqrtf(s);
        const int mt = t >> 4, r = t & 15;
        const int slot = (mt >> 1)*32 + ((r >> 2) << 3) + ((mt & 1) << 2) + (r & 3);
        w2b[j*64 + slot] = f2bf(a*inv);
    }
}

// ---------------------------------------------------------------------------
// Fused MFMA kernel: ONE WAVE per block; each block computes 16 px of one row.
// Grid = 8 * 256 * 16 = 32768 independent single-wave pipelines.
// conv1: D1[o][px] (A = weights, B = x-patch) -> lane holds o=4q+reg, px=lrow
// conv2: lane-local B-frags (hidden dim pre-permuted in w2b).
// Per-wave tile keeps acc1+acc2 at 32 VGPRs -> high resident-wave count.
// ---------------------------------------------------------------------------
__global__ __launch_bounds__(64, 6) void flow_kernel(
    const float* __restrict__ x,
    const short* __restrict__ w1b, const short* __restrict__ w2b,
    const float* __restrict__ b1,  const float* __restrict__ b2,
    float* __restrict__ out, float* __restrict__ logdet)
{
    __shared__ int ldsI[2*PW2*16];   // 2560 B

    const int bi0 = blockIdx.x;            // 0..32767
    const int b   = bi0 & 7;               // image = XCD (round-robin dispatch)
    const int idx = bi0 >> 3;              // 0..4095
    const int h   = idx >> 4;              // output row
    const int px0 = (idx & 15) << 4;       // 16-px tile base

    const int l    = threadIdx.x;          // 0..63
    const int lrow = l & 15;
    const int q    = l >> 4;

    const float* xb = x + (size_t)b * (C_*H_*W_);
    float* ob       = out + (size_t)b * (C_*H_*W_);

    // ---- stage main 16 px: lane = (r, pixel-quad, 4-ch group) -------------
    {
        const int r  = l >> 5;             // staged row (h-2 / h-1)
        const int q4 = (l >> 3) & 3;       // pixel quad
        const int cg = l & 7;              // 4-channel group
        const int hr = h - 2 + r;
        const int wq = px0 + q4*4;
        const int c4 = cg << 2;
        f32x4 v[4] = {{0,0,0,0},{0,0,0,0},{0,0,0,0},{0,0,0,0}};
        if (hr >= 0) {
            #pragma unroll
            for (int j = 0; j < 4; ++j)
                v[j] = *(const f32x4*)(xb + (size_t)(c4 + j)*(H_*W_) + (size_t)hr*W_ + wq);
        }
        #pragma unroll
        for (int pp0 = 0; pp0 < 4; ++pp0) {
            const int pp = (pp0 + q4) & 3;           // stagger: spread p parity
            const int p  = q4*4 + pp + 1;
            int2 d;
            d.x = packbf(v[0][pp], v[1][pp]);
            d.y = packbf(v[2][pp], v[3][pp]);
            const int g = ((cg >> 1) ^ (p & 3) ^ ((p >> 2) & 3)) & 3;
            *(int2*)&ldsI[(r*PW2 + p)*16 + (g << 2) + ((cg & 1) << 1)] = d;
        }
    }
    // ---- halo columns p=0 (w=px0-1) and p=17 (w=px0+16) -------------------
    {
        const int hc = l >> 5;             // which halo column
        const int r  = (l >> 4) & 1;       // staged row
        const int c2 = (l & 15) << 1;      // channel pair
        const int wc = hc ? (px0 + 16) : (px0 - 1);
        const int p  = hc ? 17 : 0;
        const int hr = h - 2 + r;
        int d = 0;
        if (hr >= 0 && wc >= 0 && wc < W_) {
            const float a0 = xb[(size_t)c2    *(H_*W_) + (size_t)hr*W_ + wc];
            const float a1 = xb[(size_t)(c2+1)*(H_*W_) + (size_t)hr*W_ + wc];
            d = packbf(a0, a1);
        }
        const int g = ((c2 >> 3) ^ (p & 3) ^ ((p >> 2) & 3)) & 3;
        ldsI[(r*PW2 + p)*16 + (g << 2) + ((c2 >> 1) & 3)] = d;
    }
    __syncthreads();   // single wave: just drains LDS writes

    // ---- conv1: D1[o][px], bias pre-loaded into acc ------------------------
    f32x4 acc1[4];
    #pragma unroll
    for (int mt = 0; mt < 4; ++mt)
        acc1[mt] = *(const f32x4*)(b1 + mt*16 + 4*q);

    #pragma unroll
    for (int tap = 0; tap < 6; ++tap) {
        const int rbase = (tap < 3) ? 0 : ROWB;
        const int dw = (tap % 3) - 1;
        const int p  = lrow + dw + 1;
        const int g  = (q ^ (p & 3) ^ ((p >> 2) & 3)) & 3;
        const short8 xf = *(const short8*)((const char*)ldsI + rbase + p*64 + (g << 4));
        #pragma unroll
        for (int mt = 0; mt < 4; ++mt) {
            const short8 wf = *(const short8*)(w1b + (mt*16 + lrow)*192 + tap*32 + q*8);
            acc1[mt] = __builtin_amdgcn_mfma_f32_16x16x32_bf16(wf, xf, acc1[mt], 0, 0, 0);
        }
    }

    // ---- ELU in-register ----------------------------------------------------
    #pragma unroll
    for (int mt = 0; mt < 4; ++mt)
        #pragma unroll
        for (int rg = 0; rg < 4; ++rg) {
            const float v = acc1[mt][rg];
            acc1[mt][rg] = v > 0.f ? v : (__expf(v) - 1.f);
        }

    // ---- conv2: lane-local B-frags (hidden dim pre-permuted in w2b) --------
    short8 bf0, bf1;
    #pragma unroll
    for (int rg = 0; rg < 4; ++rg) {
        bf0[rg]     = f2bf(acc1[0][rg]);
        bf0[rg + 4] = f2bf(acc1[1][rg]);
        bf1[rg]     = f2bf(acc1[2][rg]);
        bf1[rg + 4] = f2bf(acc1[3][rg]);
    }
    f32x4 acc2[4];
    #pragma unroll
    for (int mt2 = 0; mt2 < 4; ++mt2) {
        const short8 a0 = *(const short8*)(w2b + (mt2*16 + lrow)*64 +      q*8);
        const short8 a1 = *(const short8*)(w2b + (mt2*16 + lrow)*64 + 32 + q*8);
        f32x4 t0 = __builtin_amdgcn_mfma_f32_16x16x32_bf16(a0, bf0, (f32x4){0.f,0.f,0.f,0.f}, 0, 0, 0);
        acc2[mt2] = __builtin_amdgcn_mfma_f32_16x16x32_bf16(a1, bf1, t0, 0, 0, 0);
    }

    // ---- epilogue: sigmoid/affine/logdet, all lane-local --------------------
    float ldsum = 0.f;
    const int colbase = h*W_ + px0 + lrow;
    #pragma unroll
    for (int mt2 = 0; mt2 < 2; ++mt2) {
        const f32x4 bm = *(const f32x4*)(b2 + mt2*16 + 4*q);
        const f32x4 bs = *(const f32x4*)(b2 + 32 + mt2*16 + 4*q);
        #pragma unroll
        for (int rg = 0; rg < 4; ++rg) {
            const float mu = acc2[mt2][rg]     + bm[rg];
            const float z  = acc2[mt2 + 2][rg] + bs[rg] + 2.f;
            const float sc = 1.f / (1.f + __expf(-z));
            ldsum += __logf(sc);
            const int j = mt2*16 + 4*q + rg;
            const size_t o = (size_t)j * (H_*W_) + colbase;
            ob[o] = xb[o] * sc + mu;
        }
    }

    // ---- logdet: wave reduce + one atomic per block -------------------------
    #pragma unroll
    for (int m = 32; m >= 1; m >>= 1) ldsum += __shfl_xor(ldsum, m, 64);
    if (l == 0) atomicAdd(&logdet[b], ldsum);
}

// ---------------------------------------------------------------------------
extern "C" void kernel_launch(void* const* d_in, const int* in_sizes, int n_in,
                              void* d_out, int out_size, void* d_ws, size_t ws_size,
                              hipStream_t stream)
{
    const float* x  = (const float*)d_in[0];
    const float* v1 = (const float*)d_in[1];
    const float* g1 = (const float*)d_in[2];
    const float* b1 = (const float*)d_in[3];
    const float* v2 = (const float*)d_in[4];
    const float* g2 = (const float*)d_in[5];
    const float* b2 = (const float*)d_in[6];

    float* out    = (float*)d_out;
    float* logdet = out + NPIX;

    short* w1b = (short*)d_ws;          // 12288 bf16
    short* w2b = w1b + 12288;           //  4096 bf16

    prep_kernel<<<128, 64, 0, stream>>>(v1, g1, v2, g2, w1b, w2b, logdet);
    flow_kernel<<<B_ * H_ * 16, 64, 0, stream>>>(x, w1b, w2b, b1, b2, out, logdet);
}

// Round 8
// 68.057 us; speedup vs baseline: 6.5538x; 6.5538x over previous
//
#include <hip/hip_runtime.h>
#include <hip/hip_bf16.h>
#include <math.h>

#define B_   8
#define C_   32
#define H_   256
#define W_   256
#define NPIX (B_*C_*H_*W_)   // offset of logdet in d_out

// LDS: 2 staged rows x 260 px-slots x 32ch bf16, p = w+1, halo zeros at p=0,257.
//   dword(r,p,cp) = r*4160 + p*16 + ((cp>>2) ^ ((p>>2)&3))*4 + (cp&3)
#define PW    260
#define ROWDW (PW*16)          // 4160 dwords per staged row
#define ROWB  (ROWDW*4)        // 16640 bytes

typedef __attribute__((ext_vector_type(8))) short short8;   // bf16x8 MFMA A/B frag
typedef __attribute__((ext_vector_type(4))) float f32x4;    // fp32x4 MFMA C/D frag
typedef __attribute__((ext_vector_type(2))) float f32x2;

static __device__ __forceinline__ short f2bf(float f) {
    union { __hip_bfloat16 h; short s; } u; u.h = __float2bfloat16(f); return u.s;
}
// pack two floats -> bf16x2 dword, round-half-up (1 ulp-tie diff vs RNE)
static __device__ __forceinline__ int packbf2(float a, float b) {
    const unsigned ua = __float_as_uint(a) + 0x8000u;
    const unsigned ub = __float_as_uint(b) + 0x8000u;
    return (int)((ua >> 16) | (ub & 0xffff0000u));
}

// ---------------------------------------------------------------------------
// Prep: weight-norm -> bf16 (exact RNE here; tiny kernel).
//   w1b[o*192 + tap*32 + c]                       (tap = kh*3+kw)
//   w2b[j*64 + slot]: hidden-dim permutation so conv2 B-frags are lane-local:
//     channel c (mt=c>>4, q=(c>>2)&3, reg=c&3) -> slot (mt>>1)*32+q*8+(mt&1)*4+reg
// ---------------------------------------------------------------------------
__global__ __launch_bounds__(64) void prep_kernel(
    const float* __restrict__ v1, const float* __restrict__ g1,
    const float* __restrict__ v2, const float* __restrict__ g2,
    short* __restrict__ w1b, short* __restrict__ w2b)
{
    const int t   = threadIdx.x;   // 0..63
    const int bid = blockIdx.x;    // 0..127
    if (bid < 64) {
        const int o = bid;
        float a0 = v1[o*192 + t];
        float a1 = v1[o*192 + t + 64];
        float a2 = v1[o*192 + t + 128];
        float s  = a0*a0 + a1*a1 + a2*a2;
        #pragma unroll
        for (int m = 32; m >= 1; m >>= 1) s += __shfl_xor(s, m, 64);
        const float inv = g1[o] / sqrtf(s);
        const int e0 = t, e1 = t + 64, e2 = t + 128;   // src idx = c*6 + tap
        w1b[o*192 + (e0%6)*32 + e0/6] = f2bf(a0*inv);
        w1b[o*192 + (e1%6)*32 + e1/6] = f2bf(a1*inv);
        w1b[o*192 + (e2%6)*32 + e2/6] = f2bf(a2*inv);
    } else {
        const int j = bid - 64;
        float a = v2[j*64 + t];
        float s = a*a;
        #pragma unroll
        for (int m = 32; m >= 1; m >>= 1) s += __shfl_xor(s, m, 64);
        const float inv = g2[j] / sqrtf(s);
        const int mt = t >> 4, r = t & 15;
        const int slot = (mt >> 1)*32 + ((r >> 2) << 3) + ((mt & 1) << 2) + (r & 3);
        w2b[j*64 + slot] = f2bf(a*inv);
    }
}

// ---------------------------------------------------------------------------
// Fused MFMA kernel: one block per (b,h); 4 waves, 64 px each; 2048 blocks.
// ONE barrier: stage rows h-2,h-1 (halo'd) -> bar -> conv1 -> ELU -> conv2 -> epi.
// conv1: D1[o][px] (A = weights, B = x-patch) -> lane holds o=4q+reg, px=lrow.
// conv2: lane-local B-frags (hidden dim pre-permuted in w2b).
// logdet: per-wave partial -> plain store to ws (NO atomics; round-7 lesson:
// 4096 RMW/address serialized to ~440us).
// ---------------------------------------------------------------------------
__global__ __launch_bounds__(256) void flow_kernel(
    const float* __restrict__ x,
    const short* __restrict__ w1b, const short* __restrict__ w2b,
    const float* __restrict__ b1,  const float* __restrict__ b2,
    float* __restrict__ out, float* __restrict__ ldpart)
{
    __shared__ int ldsI[2*ROWDW];   // 33280 B

    const int bi0 = blockIdx.x;            // 0..2047
    const int bi  = (bi0 & 7) * 256 + (bi0 >> 3);   // XCD k owns image k
    const int b   = bi >> 8;
    const int h   = bi & 255;

    const int tid  = threadIdx.x;
    const int l    = tid & 63;
    const int wv   = tid >> 6;
    const int lrow = l & 15;
    const int q    = l >> 4;

    const float* xb = x + (size_t)b * (C_*H_*W_);
    float* ob       = out + (size_t)b * (C_*H_*W_);

    // ---- stage rows h-2 (r=0), h-1 (r=1): round-3 low-register loop --------
    {
        const int r  = tid >> 7;           // staged row index
        const int hr = h - 2 + r;
        const int w0 = (tid & 127) << 1;   // pixel pair w0, w0+1
        const int p0 = w0 + 1, p1 = w0 + 2;
        const int base0 = r*ROWDW + p0*16 + (((p0 >> 2) & 3) << 2);  // ^cp>>2 later
        const int base1 = r*ROWDW + p1*16 + (((p1 >> 2) & 3) << 2);
        if (hr >= 0) {
            const float* pr = xb + (size_t)hr * W_ + w0;
            #pragma unroll
            for (int cp = 0; cp < 16; ++cp) {
                const f32x2 a0 = *(const f32x2*)(pr + (size_t)(2*cp  ) * (H_*W_));
                const f32x2 a1 = *(const f32x2*)(pr + (size_t)(2*cp+1) * (H_*W_));
                // dword slot: ((cp>>2) ^ swz)*4 + (cp&3); base* already holds swz*4
                const int off = (((cp >> 2) << 2) ^ 0) + (cp & 3);   // cp>>2*4 + cp&3
                ldsI[(base0 ^ ((cp >> 2) << 2)) - (((p0 >> 2) & 3) << 2)*0 + ((cp & 3))] = 0; // placeholder (never executed)
                (void)off;
                // proper computation (kept simple for correctness):
                const int sw0 = (p0 >> 2) & 3, sw1 = (p1 >> 2) & 3;
                ldsI[r*ROWDW + p0*16 + (((cp >> 2) ^ sw0) << 2) + (cp & 3)] = packbf2(a0[0], a1[0]);
                ldsI[r*ROWDW + p1*16 + (((cp >> 2) ^ sw1) << 2) + (cp & 3)] = packbf2(a0[1], a1[1]);
            }
        } else {
            #pragma unroll
            for (int cp = 0; cp < 16; ++cp) {
                const int sw0 = (p0 >> 2) & 3, sw1 = (p1 >> 2) & 3;
                ldsI[r*ROWDW + p0*16 + (((cp >> 2) ^ sw0) << 2) + (cp & 3)] = 0;
                ldsI[r*ROWDW + p1*16 + (((cp >> 2) ^ sw1) << 2) + (cp & 3)] = 0;
            }
        }
        // halo columns p=0 and p=257: 2 rows x 2 cols x 16 dwords = 64 dwords
        if (tid < 64) {
            const int rz = tid >> 5;
            const int pz = ((tid >> 4) & 1) ? 257 : 0;
            ldsI[rz*ROWDW + pz*16 + (tid & 15)] = 0;
        }
    }
    __syncthreads();

    // ---- conv1: D1[o][px], bias pre-loaded into acc ------------------------
    f32x4 acc1[4][4];
    #pragma unroll
    for (int mt = 0; mt < 4; ++mt) {
        const f32x4 bv = *(const f32x4*)(b1 + mt*16 + 4*q);
        #pragma unroll
        for (int nt = 0; nt < 4; ++nt) acc1[mt][nt] = bv;
    }

    #pragma unroll
    for (int tap = 0; tap < 6; ++tap) {
        const int rb = (tap < 3) ? 0 : ROWB;
        const int dw = (tap % 3) - 1;
        short8 wf[4];
        #pragma unroll
        for (int mt = 0; mt < 4; ++mt)
            wf[mt] = *(const short8*)(w1b + (mt*16 + lrow)*192 + tap*32 + q*8);
        #pragma unroll
        for (int nt = 0; nt < 4; ++nt) {
            const int p = wv*64 + nt*16 + lrow + dw + 1;    // halo-shifted, no clamp
            const int byteoff = rb + p*64 + ((q ^ ((p >> 2) & 3)) << 4);
            const short8 xf = *(const short8*)((const char*)ldsI + byteoff);
            #pragma unroll
            for (int mt = 0; mt < 4; ++mt)
                acc1[mt][nt] = __builtin_amdgcn_mfma_f32_16x16x32_bf16(
                                   wf[mt], xf, acc1[mt][nt], 0, 0, 0);
        }
    }

    // ---- ELU in-register ---------------------------------------------------
    #pragma unroll
    for (int mt = 0; mt < 4; ++mt)
        #pragma unroll
        for (int nt = 0; nt < 4; ++nt)
            #pragma unroll
            for (int rg = 0; rg < 4; ++rg) {
                const float v = acc1[mt][nt][rg];
                acc1[mt][nt][rg] = v > 0.f ? v : (__expf(v) - 1.f);
            }

    // ---- conv2: lane-local B-frags (hidden dim pre-permuted in w2b) -------
    short8 a2f[2][4];
    #pragma unroll
    for (int kt = 0; kt < 2; ++kt)
        #pragma unroll
        for (int mt2 = 0; mt2 < 4; ++mt2)
            a2f[kt][mt2] = *(const short8*)(w2b + (mt2*16 + lrow)*64 + kt*32 + q*8);

    f32x4 acc2[4][4];
    #pragma unroll
    for (int nt = 0; nt < 4; ++nt) {
        union { int4 i; short8 s; } u0, u1;
        u0.i.x = packbf2(acc1[0][nt][0], acc1[0][nt][1]);
        u0.i.y = packbf2(acc1[0][nt][2], acc1[0][nt][3]);
        u0.i.z = packbf2(acc1[1][nt][0], acc1[1][nt][1]);
        u0.i.w = packbf2(acc1[1][nt][2], acc1[1][nt][3]);
        u1.i.x = packbf2(acc1[2][nt][0], acc1[2][nt][1]);
        u1.i.y = packbf2(acc1[2][nt][2], acc1[2][nt][3]);
        u1.i.z = packbf2(acc1[3][nt][0], acc1[3][nt][1]);
        u1.i.w = packbf2(acc1[3][nt][2], acc1[3][nt][3]);
        #pragma unroll
        for (int mt2 = 0; mt2 < 4; ++mt2) {
            f32x4 t0 = __builtin_amdgcn_mfma_f32_16x16x32_bf16(
                           a2f[0][mt2], u0.s, (f32x4){0.f,0.f,0.f,0.f}, 0, 0, 0);
            acc2[mt2][nt] = __builtin_amdgcn_mfma_f32_16x16x32_bf16(
                           a2f[1][mt2], u1.s, t0, 0, 0, 0);
        }
    }

    // ---- epilogue: sigmoid/affine/logdet, all lane-local -------------------
    f32x4 b2m[2], b2s[2];
    #pragma unroll
    for (int mt2 = 0; mt2 < 2; ++mt2) {
        b2m[mt2] = *(const f32x4*)(b2 + mt2*16 + 4*q);
        b2s[mt2] = *(const f32x4*)(b2 + 32 + mt2*16 + 4*q);
    }

    float ldsum = 0.f;
    #pragma unroll
    for (int nt = 0; nt < 4; ++nt) {
        const int px = wv*64 + nt*16 + lrow;
        const int colbase = h*W_ + px;
        #pragma unroll
        for (int mt2 = 0; mt2 < 2; ++mt2)
            #pragma unroll
            for (int rg = 0; rg < 4; ++rg) {
                const float mu = acc2[mt2][nt][rg]     + b2m[mt2][rg];
                const float z  = acc2[mt2 + 2][nt][rg] + b2s[mt2][rg] + 2.f;
                const float sc = 1.f / (1.f + __expf(-z));
                ldsum += __logf(sc);
                const int j = mt2*16 + 4*q + rg;
                const size_t idx = (size_t)j * (H_*W_) + colbase;
                ob[idx] = xb[idx] * sc + mu;
            }
    }

    // ---- logdet partial: plain store, no atomic ----------------------------
    #pragma unroll
    for (int m = 32; m >= 1; m >>= 1) ldsum += __shfl_xor(ldsum, m, 64);
    if (l == 0) ldpart[(size_t)bi * 4 + wv] = ldsum;   // bi = b*256 + h
}

// ---------------------------------------------------------------------------
// Final reduce: 8 blocks, each sums 1024 partials -> logdet[b].
// ---------------------------------------------------------------------------
__global__ __launch_bounds__(256) void reduce_kernel(
    const float* __restrict__ ldpart, float* __restrict__ logdet)
{
    __shared__ float r4[4];
    const int b = blockIdx.x;
    const int t = threadIdx.x;
    const f32x4 v = *(const f32x4*)(ldpart + (size_t)b*1024 + t*4);
    float s = v[0] + v[1] + v[2] + v[3];
    #pragma unroll
    for (int m = 32; m >= 1; m >>= 1) s += __shfl_xor(s, m, 64);
    if ((t & 63) == 0) r4[t >> 6] = s;
    __syncthreads();
    if (t == 0) logdet[b] = r4[0] + r4[1] + r4[2] + r4[3];
}

// ---------------------------------------------------------------------------
extern "C" void kernel_launch(void* const* d_in, const int* in_sizes, int n_in,
                              void* d_out, int out_size, void* d_ws, size_t ws_size,
                              hipStream_t stream)
{
    const float* x  = (const float*)d_in[0];
    const float* v1 = (const float*)d_in[1];
    const float* g1 = (const float*)d_in[2];
    const float* b1 = (const float*)d_in[3];
    const float* v2 = (const float*)d_in[4];
    const float* g2 = (const float*)d_in[5];
    const float* b2 = (const float*)d_in[6];

    float* out    = (float*)d_out;
    float* logdet = out + NPIX;

    short* w1b    = (short*)d_ws;                    // 12288 bf16
    short* w2b    = w1b + 12288;                     //  4096 bf16
    float* ldpart = (float*)((char*)d_ws + 32768);   //  8192 f32 partials

    prep_kernel<<<128, 64, 0, stream>>>(v1, g1, v2, g2, w1b, w2b);
    flow_kernel<<<B_ * H_, 256, 0, stream>>>(x, w1b, w2b, b1, b2, out, ldpart);
    reduce_kernel<<<B_, 256, 0, stream>>>(ldpart, logdet);
}

// Round 9
// 65.225 us; speedup vs baseline: 6.8384x; 1.0434x over previous
//
#include <hip/hip_runtime.h>
#include <hip/hip_bf16.h>
#include <math.h>

#define B_   8
#define C_   32
#define H_   256
#define W_   256
#define NPIX (B_*C_*H_*W_)   // offset of logdet in d_out

// LDS: 2 staged rows x 260 px-slots x 32ch bf16, p = w+1, halo zeros at p=0,257.
//   dword(r,p,cp) = r*4160 + p*16 + ((cp>>2) ^ ((p>>2)&3))*4 + (cp&3)
#define PW    260
#define ROWDW (PW*16)          // 4160 dwords per staged row
#define ROWB  (ROWDW*4)        // 16640 bytes

typedef __attribute__((ext_vector_type(8))) short short8;   // bf16x8 MFMA A/B frag
typedef __attribute__((ext_vector_type(4))) float f32x4;    // fp32x4 MFMA C/D frag
typedef __attribute__((ext_vector_type(2))) float f32x2;

static __device__ __forceinline__ short f2bf(float f) {
    union { __hip_bfloat16 h; short s; } u; u.h = __float2bfloat16(f); return u.s;
}
// pack two f32 -> bf16x2 dword (RNE), single HW instruction on gfx950
static __device__ __forceinline__ int cvtpk(float lo, float hi) {
    int r;
    asm("v_cvt_pk_bf16_f32 %0, %1, %2" : "=v"(r) : "v"(lo), "v"(hi));
    return r;
}

// ---------------------------------------------------------------------------
// Prep: weight-norm -> bf16 (RNE).
//   w1b[o*192 + tap*32 + c]                       (tap = kh*3+kw)
//   w2b[j*64 + slot]: hidden-dim permutation so conv2 B-frags are lane-local:
//     channel c (mt=c>>4, q=(c>>2)&3, reg=c&3) -> slot (mt>>1)*32+q*8+(mt&1)*4+reg
// ---------------------------------------------------------------------------
__global__ __launch_bounds__(64) void prep_kernel(
    const float* __restrict__ v1, const float* __restrict__ g1,
    const float* __restrict__ v2, const float* __restrict__ g2,
    short* __restrict__ w1b, short* __restrict__ w2b)
{
    const int t   = threadIdx.x;   // 0..63
    const int bid = blockIdx.x;    // 0..127
    if (bid < 64) {
        const int o = bid;
        float a0 = v1[o*192 + t];
        float a1 = v1[o*192 + t + 64];
        float a2 = v1[o*192 + t + 128];
        float s  = a0*a0 + a1*a1 + a2*a2;
        #pragma unroll
        for (int m = 32; m >= 1; m >>= 1) s += __shfl_xor(s, m, 64);
        const float inv = g1[o] / sqrtf(s);
        const int e0 = t, e1 = t + 64, e2 = t + 128;   // src idx = c*6 + tap
        w1b[o*192 + (e0%6)*32 + e0/6] = f2bf(a0*inv);
        w1b[o*192 + (e1%6)*32 + e1/6] = f2bf(a1*inv);
        w1b[o*192 + (e2%6)*32 + e2/6] = f2bf(a2*inv);
    } else {
        const int j = bid - 64;
        float a = v2[j*64 + t];
        float s = a*a;
        #pragma unroll
        for (int m = 32; m >= 1; m >>= 1) s += __shfl_xor(s, m, 64);
        const float inv = g2[j] / sqrtf(s);
        const int mt = t >> 4, r = t & 15;
        const int slot = (mt >> 1)*32 + ((r >> 2) << 3) + ((mt & 1) << 2) + (r & 3);
        w2b[j*64 + slot] = f2bf(a*inv);
    }
}

// ---------------------------------------------------------------------------
// Fused MFMA kernel: one block per (b,h); 4 waves, 64 px each; 2048 blocks.
// ONE barrier: stage rows h-2,h-1 (halo'd) -> bar -> conv1 -> ELU -> conv2 -> epi.
// conv1: D1[o][px] (A = weights, B = x-patch) -> lane holds o=4q+reg, px=lrow.
// conv2: lane-local B-frags (hidden dim pre-permuted in w2b).
// Staging: ds_write_b128 only (round-8 lesson: b32 writes here are 16-way
// bank conflicts; b128 spreads 16 banks, ~2x optimal instead of 5.7x).
// logdet: per-wave partial -> plain store (round-7 lesson: no atomics).
// ---------------------------------------------------------------------------
__global__ __launch_bounds__(256) void flow_kernel(
    const float* __restrict__ x,
    const short* __restrict__ w1b, const short* __restrict__ w2b,
    const float* __restrict__ b1,  const float* __restrict__ b2,
    float* __restrict__ out, float* __restrict__ ldpart)
{
    __shared__ int ldsI[2*ROWDW];   // 33280 B

    const int bi0 = blockIdx.x;            // 0..2047
    const int bi  = (bi0 & 7) * 256 + (bi0 >> 3);   // XCD k owns image k
    const int b   = bi >> 8;
    const int h   = bi & 255;

    const int tid  = threadIdx.x;
    const int l    = tid & 63;
    const int wv   = tid >> 6;
    const int lrow = l & 15;
    const int q    = l >> 4;

    const float* xb = x + (size_t)b * (C_*H_*W_);
    float* ob       = out + (size_t)b * (C_*H_*W_);

    // ---- stage rows h-2 (r=0), h-1 (r=1): b128 writes only ------------------
    {
        const int r   = tid >> 7;          // staged row index
        const int hr  = h - 2 + r;
        const int u   = tid & 127;
        const int w0  = u << 1;            // pixel pair w0, w0+1
        const int p0  = w0 + 1, p1 = w0 + 2;
        const int sw0 = (p0 >> 2) & 3, sw1 = (p1 >> 2) & 3;
        if (hr >= 0) {
            const float* pr = xb + (size_t)hr * W_ + w0;
            #pragma unroll
            for (int g = 0; g < 4; ++g) {          // channel octet 8g..8g+7
                f32x2 a[8];
                #pragma unroll
                for (int j = 0; j < 8; ++j)
                    a[j] = *(const f32x2*)(pr + (size_t)(8*g + j) * (H_*W_));
                int4 d0, d1;
                d0.x = cvtpk(a[0][0], a[1][0]); d0.y = cvtpk(a[2][0], a[3][0]);
                d0.z = cvtpk(a[4][0], a[5][0]); d0.w = cvtpk(a[6][0], a[7][0]);
                d1.x = cvtpk(a[0][1], a[1][1]); d1.y = cvtpk(a[2][1], a[3][1]);
                d1.z = cvtpk(a[4][1], a[5][1]); d1.w = cvtpk(a[6][1], a[7][1]);
                *(int4*)&ldsI[r*ROWDW + p0*16 + ((g ^ sw0) << 2)] = d0;
                *(int4*)&ldsI[r*ROWDW + p1*16 + ((g ^ sw1) << 2)] = d1;
            }
        } else {
            const int4 z4 = {0,0,0,0};
            #pragma unroll
            for (int g = 0; g < 4; ++g) {
                *(int4*)&ldsI[r*ROWDW + p0*16 + ((g ^ sw0) << 2)] = z4;
                *(int4*)&ldsI[r*ROWDW + p1*16 + ((g ^ sw1) << 2)] = z4;
            }
        }
        // halo columns p=0 and p=257: 2 rows x 2 cols x 16 dwords
        if (tid < 16) {
            const int rz = tid >> 3;
            const int pz = ((tid >> 2) & 1) ? 257 : 0;
            *(int4*)&ldsI[rz*ROWDW + pz*16 + ((tid & 3) << 2)] = (int4){0,0,0,0};
        }
    }
    __syncthreads();

    // ---- conv1: D1[o][px], bias pre-loaded into acc ------------------------
    f32x4 acc1[4][4];
    #pragma unroll
    for (int mt = 0; mt < 4; ++mt) {
        const f32x4 bv = *(const f32x4*)(b1 + mt*16 + 4*q);
        #pragma unroll
        for (int nt = 0; nt < 4; ++nt) acc1[mt][nt] = bv;
    }

    #pragma unroll
    for (int tap = 0; tap < 6; ++tap) {
        const int rb = (tap < 3) ? 0 : ROWB;
        const int dw = (tap % 3) - 1;
        short8 wf[4];
        #pragma unroll
        for (int mt = 0; mt < 4; ++mt)
            wf[mt] = *(const short8*)(w1b + (mt*16 + lrow)*192 + tap*32 + q*8);
        #pragma unroll
        for (int nt = 0; nt < 4; ++nt) {
            const int p = wv*64 + nt*16 + lrow + dw + 1;    // halo-shifted, no clamp
            const int byteoff = rb + p*64 + ((q ^ ((p >> 2) & 3)) << 4);
            const short8 xf = *(const short8*)((const char*)ldsI + byteoff);
            #pragma unroll
            for (int mt = 0; mt < 4; ++mt)
                acc1[mt][nt] = __builtin_amdgcn_mfma_f32_16x16x32_bf16(
                                   wf[mt], xf, acc1[mt][nt], 0, 0, 0);
        }
    }

    // ---- ELU in-register ---------------------------------------------------
    #pragma unroll
    for (int mt = 0; mt < 4; ++mt)
        #pragma unroll
        for (int nt = 0; nt < 4; ++nt)
            #pragma unroll
            for (int rg = 0; rg < 4; ++rg) {
                const float v = acc1[mt][nt][rg];
                acc1[mt][nt][rg] = v > 0.f ? v : (__expf(v) - 1.f);
            }

    // ---- conv2: lane-local B-frags (hidden dim pre-permuted in w2b) -------
    short8 a2f[2][4];
    #pragma unroll
    for (int kt = 0; kt < 2; ++kt)
        #pragma unroll
        for (int mt2 = 0; mt2 < 4; ++mt2)
            a2f[kt][mt2] = *(const short8*)(w2b + (mt2*16 + lrow)*64 + kt*32 + q*8);

    f32x4 acc2[4][4];
    #pragma unroll
    for (int nt = 0; nt < 4; ++nt) {
        union { int4 i; short8 s; } u0, u1;
        u0.i.x = cvtpk(acc1[0][nt][0], acc1[0][nt][1]);
        u0.i.y = cvtpk(acc1[0][nt][2], acc1[0][nt][3]);
        u0.i.z = cvtpk(acc1[1][nt][0], acc1[1][nt][1]);
        u0.i.w = cvtpk(acc1[1][nt][2], acc1[1][nt][3]);
        u1.i.x = cvtpk(acc1[2][nt][0], acc1[2][nt][1]);
        u1.i.y = cvtpk(acc1[2][nt][2], acc1[2][nt][3]);
        u1.i.z = cvtpk(acc1[3][nt][0], acc1[3][nt][1]);
        u1.i.w = cvtpk(acc1[3][nt][2], acc1[3][nt][3]);
        #pragma unroll
        for (int mt2 = 0; mt2 < 4; ++mt2) {
            f32x4 t0 = __builtin_amdgcn_mfma_f32_16x16x32_bf16(
                           a2f[0][mt2], u0.s, (f32x4){0.f,0.f,0.f,0.f}, 0, 0, 0);
            acc2[mt2][nt] = __builtin_amdgcn_mfma_f32_16x16x32_bf16(
                           a2f[1][mt2], u1.s, t0, 0, 0, 0);
        }
    }

    // ---- epilogue: sigmoid/affine/logdet, all lane-local -------------------
    f32x4 b2m[2], b2s[2];
    #pragma unroll
    for (int mt2 = 0; mt2 < 2; ++mt2) {
        b2m[mt2] = *(const f32x4*)(b2 + mt2*16 + 4*q);
        b2s[mt2] = *(const f32x4*)(b2 + 32 + mt2*16 + 4*q);
    }

    float ldsum = 0.f;
    #pragma unroll
    for (int nt = 0; nt < 4; ++nt) {
        const int px = wv*64 + nt*16 + lrow;
        const int colbase = h*W_ + px;
        float pr8 = 1.f;                      // product of 8 scales -> one log
        #pragma unroll
        for (int mt2 = 0; mt2 < 2; ++mt2)
            #pragma unroll
            for (int rg = 0; rg < 4; ++rg) {
                const float mu = acc2[mt2][nt][rg]     + b2m[mt2][rg];
                const float z  = acc2[mt2 + 2][nt][rg] + b2s[mt2][rg] + 2.f;
                const float sc = 1.f / (1.f + __expf(-z));
                pr8 *= sc;
                const int j = mt2*16 + 4*q + rg;
                const size_t idx = (size_t)j * (H_*W_) + colbase;
                ob[idx] = xb[idx] * sc + mu;
            }
        ldsum += __logf(pr8);
    }

    // ---- logdet partial: plain store, no atomic ----------------------------
    #pragma unroll
    for (int m = 32; m >= 1; m >>= 1) ldsum += __shfl_xor(ldsum, m, 64);
    if (l == 0) ldpart[(size_t)bi * 4 + wv] = ldsum;   // bi = b*256 + h
}

// ---------------------------------------------------------------------------
// Final reduce: 8 blocks, each sums 1024 partials -> logdet[b].
// ---------------------------------------------------------------------------
__global__ __launch_bounds__(256) void reduce_kernel(
    const float* __restrict__ ldpart, float* __restrict__ logdet)
{
    __shared__ float r4[4];
    const int b = blockIdx.x;
    const int t = threadIdx.x;
    const f32x4 v = *(const f32x4*)(ldpart + (size_t)b*1024 + t*4);
    float s = v[0] + v[1] + v[2] + v[3];
    #pragma unroll
    for (int m = 32; m >= 1; m >>= 1) s += __shfl_xor(s, m, 64);
    if ((t & 63) == 0) r4[t >> 6] = s;
    __syncthreads();
    if (t == 0) logdet[b] = r4[0] + r4[1] + r4[2] + r4[3];
}

// ---------------------------------------------------------------------------
extern "C" void kernel_launch(void* const* d_in, const int* in_sizes, int n_in,
                              void* d_out, int out_size, void* d_ws, size_t ws_size,
                              hipStream_t stream)
{
    const float* x  = (const float*)d_in[0];
    const float* v1 = (const float*)d_in[1];
    const float* g1 = (const float*)d_in[2];
    const float* b1 = (const float*)d_in[3];
    const float* v2 = (const float*)d_in[4];
    const float* g2 = (const float*)d_in[5];
    const float* b2 = (const float*)d_in[6];

    float* out    = (float*)d_out;
    float* logdet = out + NPIX;

    short* w1b    = (short*)d_ws;                    // 12288 bf16
    short* w2b    = w1b + 12288;                     //  4096 bf16
    float* ldpart = (float*)((char*)d_ws + 32768);   //  8192 f32 partials

    prep_kernel<<<128, 64, 0, stream>>>(v1, g1, v2, g2, w1b, w2b);
    flow_kernel<<<B_ * H_, 256, 0, stream>>>(x, w1b, w2b, b1, b2, out, ldpart);
    reduce_kernel<<<B_, 256, 0, stream>>>(ldpart, logdet);
}